// Round 22
// baseline (664.993 us; speedup 1.0000x reference)
//
#include <hip/hip_runtime.h>
#include <math.h>

// ---------------------------------------------------------------------------
// Model constants
// ---------------------------------------------------------------------------
#define BB 4
#define SS 1024
#define LL 4
#define HH 8
#define DM 512
#define DF 2048
#define DH 64
#define NS 5
#define RR 32
#define MM 128          // favor feature dims
#define NC 16           // attention chunks
#define CHK 64          // chunk size
#define QKV_N 1536      // packed q|k|v width

#define INV_SQRT10   0.316227766016838f
#define INV_SCALE    0.148650889375340f   // 1/(R*DH)^0.25
#define TEMP_SCALE   0.353553390593274f   // 64^-0.25
#define INV_SQRT_M   0.088388347648318f   // 1/sqrt(128)
#define TWO_PI       6.283185307179586f
#define PI_F         3.141592653589793f

typedef __attribute__((ext_vector_type(8))) short bf16x8;
typedef __attribute__((ext_vector_type(4))) float f32x4;

__device__ __forceinline__ unsigned short f2bf(float f) {
  union { float f; unsigned int u; } v; v.f = f;
  unsigned int r = v.u + 0x7FFFu + ((v.u >> 16) & 1u);
  return (unsigned short)(r >> 16);
}

__device__ __forceinline__ float bf2f(unsigned short u) {
  union { unsigned int u; float f; } v; v.u = (unsigned int)u << 16;
  return v.f;
}

__device__ __forceinline__ void gld_lds16(const unsigned short* g, unsigned short* l) {
  __builtin_amdgcn_global_load_lds((const __attribute__((address_space(1))) void*)g,
                                   (__attribute__((address_space(3))) void*)l,
                                   16, 0, 0);
}

// ---------------------------------------------------------------------------
// bf16 MFMA GEMM, 128x128 tile (m97-class: 4 waves, 4x4 acc/wave, 16 MFMA
// per k-step per wave). SPLITK>1: blockIdx.z owns K-slice, writes its own
// C slice (+ kz*M*N, f32 or bf16 per OUT_BF); bias added on slice 0 only.
// ---------------------------------------------------------------------------
template<int RELU, int OUT_BF, int SPLITK>
__global__ __launch_bounds__(256)
void gemm_mfma_128(const unsigned short* __restrict__ A, const unsigned short* __restrict__ Bt,
                   const float* __restrict__ bias, float* __restrict__ Cf,
                   unsigned short* __restrict__ Cbf, int M, int N, int K)
{
  __shared__ unsigned short As[128 * 32];
  __shared__ unsigned short Bs[128 * 32];
  const int tid  = threadIdx.x;
  const int w    = tid >> 6;
  const int lane = tid & 63;
  const int row0 = blockIdx.y * 128;
  const int col0 = blockIdx.x * 128;
  const int kz   = (SPLITK > 1) ? blockIdx.z : 0;
  const int Ks   = K / SPLITK;
  const int kbeg = kz * Ks;
  const int wr = (w >> 1) * 64;    // wave row quadrant
  const int wc = (w & 1) * 64;     // wave col quadrant
  const int c0 = w * 2, c1 = w * 2 + 1;        // staging slots 0..7 (16 rows each)
  const int m0 = c0 * 16 + (lane >> 2);
  const int m1 = c1 * 16 + (lane >> 2);
  const int kA = (lane & 3) * 8;

  f32x4 acc[4][4] = {};

  for (int k0 = kbeg; k0 < kbeg + Ks; k0 += 32) {
    gld_lds16(&A [(size_t)(row0 + m0) * K + k0 + kA], &As[c0 * 512]);
    gld_lds16(&A [(size_t)(row0 + m1) * K + k0 + kA], &As[c1 * 512]);
    gld_lds16(&Bt[(size_t)(col0 + m0) * K + k0 + kA], &Bs[c0 * 512]);
    gld_lds16(&Bt[(size_t)(col0 + m1) * K + k0 + kA], &Bs[c1 * 512]);
    __syncthreads();
    const int rA = wr + (lane & 15);
    const int rB = wc + (lane & 15);
    const int kk = (lane >> 4) * 8;
    bf16x8 af[4], bfr[4];
#pragma unroll
    for (int i = 0; i < 4; ++i) {
      af[i]  = *reinterpret_cast<const bf16x8*>(&As[(rA + i * 16) * 32 + kk]);
      bfr[i] = *reinterpret_cast<const bf16x8*>(&Bs[(rB + i * 16) * 32 + kk]);
    }
#pragma unroll
    for (int mi = 0; mi < 4; ++mi)
#pragma unroll
      for (int ni = 0; ni < 4; ++ni)
        acc[mi][ni] = __builtin_amdgcn_mfma_f32_16x16x32_bf16(af[mi], bfr[ni], acc[mi][ni], 0, 0, 0);
    __syncthreads();
  }
  const int cr = (lane >> 4) * 4;
  const int cc = lane & 15;
  float* Cfo = Cf ? (Cf + (size_t)kz * M * N) : Cf;
  unsigned short* Cbo = Cbf ? (Cbf + (size_t)kz * M * N) : Cbf;
#pragma unroll
  for (int mi = 0; mi < 4; ++mi) {
#pragma unroll
    for (int ni = 0; ni < 4; ++ni) {
      const int col = col0 + wc + ni * 16 + cc;
      const float bv = (kz == 0) ? bias[col] : 0.f;
#pragma unroll
      for (int r = 0; r < 4; ++r) {
        const int row = row0 + wr + mi * 16 + cr + r;
        float v = acc[mi][ni][r] + bv;
        if (RELU) v = fmaxf(v, 0.f);
        if (OUT_BF) Cbo[(size_t)row * N + col] = f2bf(v);
        else        Cfo[(size_t)row * N + col] = v;
      }
    }
  }
}

// ---------------------------------------------------------------------------
// prep_all: fuses ALL prologue work into one launch.
// ---------------------------------------------------------------------------
#define PR_T0   4096
#define PR_W1   8192
#define PR_W2   12288
#define PR_OM   12304
#define PR_PB   12328
#define PR_SP   15224
#define PR_CV   17272

__global__ __launch_bounds__(256)
void prep_all(const float* __restrict__ x,
              const float* __restrict__ Wq, const float* __restrict__ Wk,
              const float* __restrict__ Wv, const float* __restrict__ Wo,
              const float* __restrict__ W1, const float* __restrict__ W2,
              const float* __restrict__ omega,
              const float* __restrict__ bq, const float* __restrict__ bk,
              const float* __restrict__ bv,
              const float* __restrict__ gains, const float* __restrict__ noise,
              const float* __restrict__ gate, const float* __restrict__ gnoise,
              const float* __restrict__ offsets, const float* __restrict__ freqs,
              unsigned short* __restrict__ curbf,
              unsigned short* __restrict__ Wqkvt, unsigned short* __restrict__ Wot,
              unsigned short* __restrict__ W1t, unsigned short* __restrict__ W2t,
              unsigned short* __restrict__ omgT,
              float* __restrict__ bqkv,
              unsigned short* __restrict__ zpb, unsigned short* __restrict__ wbb,
              float2* __restrict__ offcs, float* __restrict__ omg)
{
  const int bid = blockIdx.x;
  const int tid = threadIdx.x;

  if (bid < PR_OM) {
    // ---- transpose tasks ----
    const float* W; unsigned short* Wt; int K, N, bx, by;
    if (bid < PR_T0) {
      const int mat = bid >> 10;          // 0..3
      const int local = bid & 1023;
      bx = local & 15; by = (local >> 4) & 15;
      const int l = local >> 8;
      K = DM; N = DM;
      if (mat == 0)      { W = Wq + (size_t)l * DM * DM; Wt = Wqkvt + (size_t)l * QKV_N * DM; }
      else if (mat == 1) { W = Wk + (size_t)l * DM * DM; Wt = Wqkvt + (size_t)l * QKV_N * DM + (size_t)512 * DM; }
      else if (mat == 2) { W = Wv + (size_t)l * DM * DM; Wt = Wqkvt + (size_t)l * QKV_N * DM + (size_t)1024 * DM; }
      else               { W = Wo + (size_t)l * DM * DM; Wt = Wot + (size_t)l * DM * DM; }
    } else if (bid < PR_W1) {
      const int local = bid - PR_T0;
      bx = local & 63; by = (local >> 6) & 15;
      const int l = local >> 10;
      K = DM; N = DF;
      W = W1 + (size_t)l * DM * DF; Wt = W1t + (size_t)l * DF * DM;
    } else if (bid < PR_W2) {
      const int local = bid - PR_W1;
      bx = local & 15; by = (local >> 4) & 63;
      const int l = local >> 10;
      K = DF; N = DM;
      W = W2 + (size_t)l * DF * DM; Wt = W2t + (size_t)l * DM * DF;
    } else {
      const int local = bid - PR_W2;
      bx = local & 1; by = (local >> 1) & 1;
      const int l = local >> 2;
      K = DH; N = MM / 2;
      W = omega + (size_t)l * DH * (MM / 2); Wt = omgT + (size_t)l * 4096;
    }
    __shared__ float tile[32][33];
    const int k0 = by * 32, n0 = bx * 32;
    const int tx = tid & 31, ty = tid >> 5;
#pragma unroll
    for (int j = 0; j < 4; ++j)
      tile[ty + 8 * j][tx] = W[(size_t)(k0 + ty + 8 * j) * N + n0 + tx];
    __syncthreads();
#pragma unroll
    for (int j = 0; j < 4; ++j)
      Wt[(size_t)(n0 + ty + 8 * j) * K + k0 + tx] = f2bf(tile[tx][ty + 8 * j]);
  } else if (bid < PR_PB) {
    // ---- pack_bias ----
    const int local = bid - PR_OM;
    const int l = local / 6;
    const int i = (local % 6) * 256 + tid;
    if (i < QKV_N)
      bqkv[l * QKV_N + i] = (i < 512) ? bq[l * DM + i] : (i < 1024) ? bk[l * DM + i - 512]
                                                                    : bv[l * DM + i - 1024];
  } else if (bid < PR_SP) {
    // ---- spe precompute ----
    const int i = (bid - PR_PB) * 256 + tid;
    const int NZ = LL * HH * RR * 10 * DH;      // 655360
    const int NW = LL * HH * RR * DH;           // 65536
    const int NO = LL * HH * DH * NS;           // 10240
    if (i < NZ) {
      const int d = i & 63;
      int j = i >> 6;
      const int k = j % 10; j /= 10;
      const int r = j & 31; j >>= 5;
      const int h = j & 7;  const int l = j >> 3;
      const int lhd = (l * HH + h) * DH + d;
      const float ga = gains[lhd * NS + (k >> 1)];
      const float sp = (ga > 20.f) ? ga : log1pf(__expf(ga));
      const float gg = 1.f / (1.f + __expf(-gate[lhd]));
      const float c1 = sqrtf(fmaxf(1.f - gg, 0.f));
      const float nz = noise[((size_t)lhd * 10 + k) * 32 + r];
      zpb[i] = f2bf(nz * sp * c1 * (INV_SQRT10 * INV_SCALE * TEMP_SCALE));
    } else if (i < NZ + NW) {
      int j = i - NZ;
      const int d = j & 63; j >>= 6;
      const int r = j & 31; j >>= 5;
      const int h = j & 7;  const int l = j >> 3;
      const int lhd = (l * HH + h) * DH + d;
      const float gg = 1.f / (1.f + __expf(-gate[lhd]));
      wbb[i - NZ] = f2bf(sqrtf(gg) * gnoise[(size_t)lhd * 32 + r] * (INV_SCALE * TEMP_SCALE));
    } else if (i < NZ + NW + NO) {
      const int j = i - NZ - NW;
      float sn, cn;
      __sincosf(offsets[j], &sn, &cn);
      offcs[j] = make_float2(cn, sn);
    } else if (i < NZ + NW + 2 * NO) {
      const int j = i - NZ - NW - NO;
      omg[j] = PI_F / (1.f + __expf(-freqs[j]));
    }
  } else {
    // ---- x -> bf16 (vectorized by 4) ----
    const int i = (bid - PR_SP) * 256 + tid;
    const int n4 = BB * SS * DM / 4;
    if (i < n4) {
      const float4 v = reinterpret_cast<const float4*>(x)[i];
      ushort4 o;
      o.x = f2bf(v.x); o.y = f2bf(v.y); o.z = f2bf(v.z); o.w = f2bf(v.w);
      reinterpret_cast<ushort4*>(curbf)[i] = o;
    }
  }
}

// ---------------------------------------------------------------------------
// spe_xhat (fused, bf16 qkv, omg table): per (s,h). Builds qb/kb, MFMA ->
// xq/xk, then FAVOR: xq/xk back into rQ/rK rows 0-3, omega-MFMA, exp -> QfKfB.
// Tails (write-back + exp epilogue) spread across all 64 lanes via shfl.
// ---------------------------------------------------------------------------
__global__ __launch_bounds__(256)
void spe_xhat(const float* __restrict__ omg, const float2* __restrict__ offcs,
              const unsigned short* __restrict__ zpb, const unsigned short* __restrict__ wbb,
              const unsigned short* __restrict__ qkvb, const unsigned short* __restrict__ omgT,
              unsigned short* __restrict__ QfKfB)
{
  const int s = blockIdx.x;
  const int h = blockIdx.y;
  const int t = threadIdx.x;
  const int w = t >> 6;
  const int lane = t & 63;
  __shared__ float omqT[10][64];
  __shared__ float omkT[10][64];
  __shared__ unsigned short qbT[64 * 64];
  __shared__ unsigned short kbT[64 * 64];
  __shared__ unsigned short rQ[16 * 64];
  __shared__ unsigned short rK[16 * 64];
  __shared__ float hqp[4][8];
  __shared__ float hnl[8];   // [qk*4 + b]

  // phase A: sincos(omg*s) for k; q via rotation by precomputed offset sincos
  for (int e = t; e < DH * NS; e += 256) {
    const int d = e / NS, ns = e - d * NS;
    const float om = omg[(h * DH + d) * NS + ns];
    float sn, cn;
    __sincosf(om * (float)s, &sn, &cn);
    const float2 oc = offcs[(h * DH + d) * NS + ns];
    omkT[2 * ns][d]     = cn;
    omkT[2 * ns + 1][d] = sn;
    omqT[2 * ns][d]     = cn * oc.x - sn * oc.y;
    omqT[2 * ns + 1][d] = sn * oc.x + cn * oc.y;
  }
  // q/k row staging: vectorized bf16x8 copies (rows 0-3), zero rows 4-15
  if (t < 64) {
    const int isK = t >> 5;
    const int b = (t >> 3) & 3;
    const int j = t & 7;
    const unsigned short* src = qkvb + ((size_t)b * SS + s) * QKV_N + isK * 512 + h * DH + j * 8;
    unsigned short* dst = (isK ? rK : rQ) + b * 64 + ((j ^ b) << 3);
    *reinterpret_cast<bf16x8*>(dst) = *reinterpret_cast<const bf16x8*>(src);
  } else if (t < 256) {
    const int i = t - 64;   // 0..191
    bf16x8 z = {};
    if (i < 96) *reinterpret_cast<bf16x8*>(&rQ[256 + i * 8]) = z;
    else        *reinterpret_cast<bf16x8*>(&rK[256 + (i - 96) * 8]) = z;
  }
  __syncthreads();
  // phase B: build qbT/kbT. thread = (r = t>>3, d-octet dg = t&7)
  {
    const int r = t >> 3, dg = t & 7, d0 = dg * 8;
    float accq[8] = {}, acck[8] = {};
    const unsigned short* zr = zpb + (size_t)(h * RR + r) * 10 * 64 + d0;
#pragma unroll
    for (int k = 0; k < 10; ++k) {
      const bf16x8 zv = *reinterpret_cast<const bf16x8*>(zr + (size_t)k * 64);
      const float4 oq0 = *reinterpret_cast<const float4*>(&omqT[k][d0]);
      const float4 oq1 = *reinterpret_cast<const float4*>(&omqT[k][d0 + 4]);
      const float4 ok0 = *reinterpret_cast<const float4*>(&omkT[k][d0]);
      const float4 ok1 = *reinterpret_cast<const float4*>(&omkT[k][d0 + 4]);
      float zf[8];
#pragma unroll
      for (int j = 0; j < 8; ++j) zf[j] = bf2f((unsigned short)zv[j]);
      accq[0] += zf[0] * oq0.x; accq[1] += zf[1] * oq0.y;
      accq[2] += zf[2] * oq0.z; accq[3] += zf[3] * oq0.w;
      accq[4] += zf[4] * oq1.x; accq[5] += zf[5] * oq1.y;
      accq[6] += zf[6] * oq1.z; accq[7] += zf[7] * oq1.w;
      acck[0] += zf[0] * ok0.x; acck[1] += zf[1] * ok0.y;
      acck[2] += zf[2] * ok0.z; acck[3] += zf[3] * ok0.w;
      acck[4] += zf[4] * ok1.x; acck[5] += zf[5] * ok1.y;
      acck[6] += zf[6] * ok1.z; acck[7] += zf[7] * ok1.w;
    }
    bf16x8 qv, kv;
#pragma unroll
    for (int j = 0; j < 8; ++j) {
      qv[j] = (short)f2bf(accq[j]);
      kv[j] = (short)f2bf(acck[j]);
    }
    const int sd0 = d0 ^ ((r & 7) << 3);
    *reinterpret_cast<bf16x8*>(&qbT[r * 64 + sd0]) = qv;
    *reinterpret_cast<bf16x8*>(&kbT[r * 64 + sd0]) = kv;
    const bf16x8 wv = *reinterpret_cast<const bf16x8*>(&wbb[(size_t)(h * RR + r) * 64 + d0]);
    *reinterpret_cast<bf16x8*>(&qbT[(32 + r) * 64 + sd0]) = wv;
    *reinterpret_cast<bf16x8*>(&kbT[(32 + r) * 64 + sd0]) = wv;
  }
  __syncthreads();
  // MFMA: xq/xk = rows @ qb/kb
  f32x4 aq = {0.f, 0.f, 0.f, 0.f}, ak = {0.f, 0.f, 0.f, 0.f};
  const int arow = lane & 15;
  const int colr = w * 16 + (lane & 15);
#pragma unroll
  for (int kt = 0; kt < 2; ++kt) {
    const int g = kt * 4 + (lane >> 4);
    const bf16x8 fAq = *reinterpret_cast<const bf16x8*>(&rQ[arow * 64 + ((g ^ (arow & 7)) << 3)]);
    const bf16x8 fAk = *reinterpret_cast<const bf16x8*>(&rK[arow * 64 + ((g ^ (arow & 7)) << 3)]);
    const bf16x8 fBq = *reinterpret_cast<const bf16x8*>(&qbT[colr * 64 + ((g ^ (colr & 7)) << 3)]);
    const bf16x8 fBk = *reinterpret_cast<const bf16x8*>(&kbT[colr * 64 + ((g ^ (colr & 7)) << 3)]);
    aq = __builtin_amdgcn_mfma_f32_16x16x32_bf16(fAq, fBq, aq, 0, 0, 0);
    ak = __builtin_amdgcn_mfma_f32_16x16x32_bf16(fAk, fBk, ak, 0, 0, 0);
  }
  // half-norm partials (reduce over the 16 lanes of this lane-group)
  float rq[4], rk2[4];
#pragma unroll
  for (int r = 0; r < 4; ++r) { rq[r] = aq[r] * aq[r]; rk2[r] = ak[r] * ak[r]; }
#pragma unroll
  for (int off = 1; off < 16; off <<= 1) {
#pragma unroll
    for (int r = 0; r < 4; ++r) {
      rq[r]  += __shfl_xor(rq[r],  off, 64);
      rk2[r] += __shfl_xor(rk2[r], off, 64);
    }
  }
  if (lane == 0) {
#pragma unroll
    for (int r = 0; r < 4; ++r) { hqp[w][r] = rq[r]; hqp[w][4 + r] = rk2[r]; }
  }
  __syncthreads();   // all rQ/rK reads done; hqp complete

  // hn finalize into LDS
  if (t < 8) {
    const int b = t & 3;
    const int ko = (t >> 2) * 4;
    hnl[t] = 0.5f * (hqp[0][ko + b] + hqp[1][ko + b] + hqp[2][ko + b] + hqp[3][ko + b]);
  }
  // write xq/xk (bf16) back into rQ/rK rows 0-3 — spread across all 64 lanes.
  // Real MFMA rows live in lanes 0-15 (g=0): shfl with full exec, src 0-15.
  {
    const int rr = lane >> 4, cc2 = lane & 15;
    const float a0 = __shfl(aq[0], cc2, 64), a1 = __shfl(aq[1], cc2, 64);
    const float a2 = __shfl(aq[2], cc2, 64), a3 = __shfl(aq[3], cc2, 64);
    const float b0 = __shfl(ak[0], cc2, 64), b1 = __shfl(ak[1], cc2, 64);
    const float b2 = __shfl(ak[2], cc2, 64), b3 = __shfl(ak[3], cc2, 64);
    const float va = rr == 0 ? a0 : rr == 1 ? a1 : rr == 2 ? a2 : a3;
    const float vb = rr == 0 ? b0 : rr == 1 ? b1 : rr == 2 ? b2 : b3;
    const int d = w * 16 + cc2;
    rQ[rr * 64 + (d ^ (rr << 3))] = f2bf(va);
    rK[rr * 64 + (d ^ (rr << 3))] = f2bf(vb);
  }
  __syncthreads();

  // omega MFMA: u = xhat @ omgT^T (B-fragment straight from global/L2)
  f32x4 uq = {0.f, 0.f, 0.f, 0.f}, uk = {0.f, 0.f, 0.f, 0.f};
  const int ocol = w * 16 + (lane & 15);
#pragma unroll
  for (int kt = 0; kt < 2; ++kt) {
    const int g = kt * 4 + (lane >> 4);
    const bf16x8 fAq = *reinterpret_cast<const bf16x8*>(&rQ[arow * 64 + ((g ^ (arow & 7)) << 3)]);
    const bf16x8 fAk = *reinterpret_cast<const bf16x8*>(&rK[arow * 64 + ((g ^ (arow & 7)) << 3)]);
    const bf16x8 fB  = *reinterpret_cast<const bf16x8*>(&omgT[(size_t)ocol * 64 + g * 8]);
    uq = __builtin_amdgcn_mfma_f32_16x16x32_bf16(fAq, fB, uq, 0, 0, 0);
    uk = __builtin_amdgcn_mfma_f32_16x16x32_bf16(fAk, fB, uk, 0, 0, 0);
  }
  // epilogue: exp(+/-u - hn) -> QfKfB, spread across all 64 lanes
  {
    const int rr = lane >> 4, cc2 = lane & 15;
    const float q0 = __shfl(uq[0], cc2, 64), q1 = __shfl(uq[1], cc2, 64);
    const float q2 = __shfl(uq[2], cc2, 64), q3 = __shfl(uq[3], cc2, 64);
    const float k0 = __shfl(uk[0], cc2, 64), k1 = __shfl(uk[1], cc2, 64);
    const float k2 = __shfl(uk[2], cc2, 64), k3 = __shfl(uk[3], cc2, 64);
    const float vq = rr == 0 ? q0 : rr == 1 ? q1 : rr == 2 ? q2 : q3;
    const float vk = rr == 0 ? k0 : rr == 1 ? k1 : rr == 2 ? k2 : k3;
    const float hq = hnl[rr], hk = hnl[4 + rr];
    const size_t rowq = ((size_t)rr * SS + s) * HH + h;
    const size_t rowk = rowq + (size_t)BB * SS * HH;
    const int oc = w * 16 + cc2;
    QfKfB[rowq * MM + oc]      = f2bf(__expf( vq - hq) * INV_SQRT_M);
    QfKfB[rowq * MM + oc + 64] = f2bf(__expf(-vq - hq) * INV_SQRT_M);
    QfKfB[rowk * MM + oc]      = f2bf(__expf( vk - hk) * INV_SQRT_M);
    QfKfB[rowk * MM + oc + 64] = f2bf(__expf(-vk - hk) * INV_SQRT_M);
  }
}

// ---------------------------------------------------------------------------
// Attention pass A — MFMA: SchB[m][d] (bf16) = K^T V per chunk; kch f32.
// ---------------------------------------------------------------------------
__global__ __launch_bounds__(256)
void attn_chunk_sums(const unsigned short* __restrict__ KfB, const unsigned short* __restrict__ qkvb,
                     unsigned short* __restrict__ SchB, float* __restrict__ kch)
{
  const int c = blockIdx.x, h = blockIdx.y, b = blockIdx.z;
  const int tid = threadIdx.x;
  const int w = tid >> 6, lane = tid & 63;
  __shared__ unsigned short KcT[128 * 64];  // [m][t], t ^= (m&7)<<3
  __shared__ unsigned short VT[64 * 64];    // [d][t], t ^= (d&7)<<3
  const size_t srow0 = (size_t)b * SS + c * CHK;

  for (int i = tid; i < 8192; i += 256) {
    const int m = i & 127, t = i >> 7;
    KcT[m * 64 + (t ^ ((m & 7) << 3))] = KfB[((srow0 + t) * HH + h) * MM + m];
  }
  for (int i = tid; i < 512; i += 256) {
    const int d = i & 63, oct = i >> 6;
    const unsigned short* src = qkvb + (srow0 + oct * 8) * QKV_N + 1024 + h * DH + d;
    bf16x8 v;
#pragma unroll
    for (int j = 0; j < 8; ++j) v[j] = (short)src[(size_t)j * QKV_N];
    *reinterpret_cast<bf16x8*>(&VT[d * 64 + ((oct << 3) ^ ((d & 7) << 3))]) = v;
  }
  __syncthreads();

  const int kk = (lane >> 4) * 8;
  f32x4 acc[2][4] = {};
#pragma unroll
  for (int kc = 0; kc < 2; ++kc) {
    const int k = kc * 32 + kk;
#pragma unroll
    for (int mi = 0; mi < 2; ++mi) {
      const int mA = w * 32 + mi * 16 + (lane & 15);
      const bf16x8 a = *reinterpret_cast<const bf16x8*>(&KcT[mA * 64 + (k ^ ((mA & 7) << 3))]);
#pragma unroll
      for (int ni = 0; ni < 4; ++ni) {
        const int dB = ni * 16 + (lane & 15);
        const bf16x8 bb = *reinterpret_cast<const bf16x8*>(&VT[dB * 64 + (k ^ ((dB & 7) << 3))]);
        acc[mi][ni] = __builtin_amdgcn_mfma_f32_16x16x32_bf16(a, bb, acc[mi][ni], 0, 0, 0);
      }
    }
  }
  const size_t base = (((size_t)b * HH + h) * NC + c);
  unsigned short* So = SchB + base * (MM * DH);
  const int cr = (lane >> 4) * 4, cc = lane & 15;
#pragma unroll
  for (int mi = 0; mi < 2; ++mi)
#pragma unroll
    for (int ni = 0; ni < 4; ++ni)
#pragma unroll
      for (int r = 0; r < 4; ++r)
        So[(size_t)(w * 32 + mi * 16 + cr + r) * DH + ni * 16 + cc] = f2bf(acc[mi][ni][r]);
  // kch
  {
    const int m = tid >> 1, half = tid & 1;
    float ks = 0.f;
#pragma unroll
    for (int j = 0; j < 32; ++j) {
      const int t2 = half * 32 + j;
      ks += bf2f(KcT[m * 64 + (t2 ^ ((m & 7) << 3))]);
    }
    ks += __shfl_xor(ks, 1, 64);
    if (half == 0) kch[base * MM + m] = ks;
  }
}

// ---------------------------------------------------------------------------
// Attention pass B: exclusive scan over chunks (bf16 Sch, f32 accumulation,
// 4-wide vectorized accesses)
// ---------------------------------------------------------------------------
__global__ __launch_bounds__(256)
void attn_scan(unsigned short* __restrict__ SchB, float* __restrict__ kch)
{
  const int bh = blockIdx.x, part = blockIdx.y;
  const int t = threadIdx.x;
  unsigned short* base = SchB + (size_t)bh * NC * (MM * DH);
  {
    const int e0 = part * 1024 + t * 4;   // 4 contiguous elems per thread
    float run0 = 0.f, run1 = 0.f, run2 = 0.f, run3 = 0.f;
#pragma unroll
    for (int c = 0; c < NC; ++c) {
      ushort4* p = reinterpret_cast<ushort4*>(&base[(size_t)c * (MM * DH) + e0]);
      const ushort4 v = *p;
      ushort4 o;
      o.x = f2bf(run0); o.y = f2bf(run1); o.z = f2bf(run2); o.w = f2bf(run3);
      *p = o;
      run0 += bf2f(v.x); run1 += bf2f(v.y); run2 += bf2f(v.z); run3 += bf2f(v.w);
    }
  }
  if (part == 0 && t < MM) {
    float* kb2 = kch + (size_t)bh * NC * MM;
    float run = 0.f;
#pragma unroll
    for (int c = 0; c < NC; ++c) {
      const float v = kb2[c * MM + t];
      kb2[c * MM + t] = run;
      run += v;
    }
  }
}

// ---------------------------------------------------------------------------
// Attention pass C — MFMA (bf16 Qf/Kf, bf16 V, bf16 Sch)
// ---------------------------------------------------------------------------
__global__ __launch_bounds__(256)
void attn_out(const unsigned short* __restrict__ QfKfB, const unsigned short* __restrict__ qkvb,
              const unsigned short* __restrict__ SchB, const float* __restrict__ kch,
              unsigned short* __restrict__ att)
{
  const int c = blockIdx.x, h = blockIdx.y, b = blockIdx.z;
  const int tid = threadIdx.x;
  const int w = tid >> 6;
  const int lane = tid & 63;
  __shared__ unsigned short Qc[64 * 128];   // [s][m], m ^= (s&15)<<3
  __shared__ unsigned short Sb[64 * 64];    // [s][t], t ^= (s&7)<<3
  __shared__ unsigned short KVU[12288];     // ph1: Kc; ph2: SpxT@0, VT@8192
  __shared__ float skp[MM];
  __shared__ float denl[64];

  unsigned short* Kc   = KVU;
  unsigned short* SpxT = KVU;
  unsigned short* VT   = KVU + 8192;

  const size_t srow0 = (size_t)b * SS + c * CHK;
  const unsigned short* Qg = QfKfB + (srow0 * HH + h) * MM;
  const unsigned short* Kg = Qg + (size_t)BB * SS * HH * MM;

  if (tid < MM) skp[tid] = kch[(((size_t)b * HH + h) * NC + c) * MM + tid];

  // stage Qc, Kc (bf16x8 reads, swizzled b128 writes)
  for (int i = tid; i < 1024; i += 256) {
    const int s2 = i >> 4, m8 = (i & 15) * 8;
    const int sw = m8 ^ ((s2 & 15) << 3);
    *reinterpret_cast<bf16x8*>(&Qc[s2 * 128 + sw]) =
        *reinterpret_cast<const bf16x8*>(&Qg[(size_t)s2 * (HH * MM) + m8]);
    *reinterpret_cast<bf16x8*>(&Kc[s2 * 128 + sw]) =
        *reinterpret_cast<const bf16x8*>(&Kg[(size_t)s2 * (HH * MM) + m8]);
  }
  for (int i = tid; i < 512; i += 256) {
    const int d = i & 63, oct = i >> 6;
    const unsigned short* src = qkvb + (srow0 + oct * 8) * QKV_N + 1024 + h * DH + d;
    bf16x8 v;
#pragma unroll
    for (int j = 0; j < 8; ++j) v[j] = (short)src[(size_t)j * QKV_N];
    *reinterpret_cast<bf16x8*>(&VT[d * 64 + ((oct << 3) ^ ((d & 7) << 3))]) = v;
  }
  __syncthreads();

  // phase 1: S = Qc @ Kc^T
  const int sA = w * 16 + (lane & 15);
  const int kk = (lane >> 4) * 8;
  f32x4 acc_s[4] = {};
#pragma unroll
  for (int kc = 0; kc < 4; ++kc) {
    const int k = kc * 32 + kk;
    const bf16x8 aq = *reinterpret_cast<const bf16x8*>(&Qc[sA * 128 + (k ^ ((sA & 15) << 3))]);
#pragma unroll
    for (int n = 0; n < 4; ++n) {
      const int tB = n * 16 + (lane & 15);
      const bf16x8 bq = *reinterpret_cast<const bf16x8*>(&Kc[tB * 128 + (k ^ ((tB & 15) << 3))]);
      acc_s[n] = __builtin_amdgcn_mfma_f32_16x16x32_bf16(aq, bq, acc_s[n], 0, 0, 0);
    }
  }
  __syncthreads();   // Kc reads done; KVU reusable

  // mask + den_intra + write Sb
  {
    const int g = lane >> 4;
    const int tcol = lane & 15;
    float dintra[4] = {0.f, 0.f, 0.f, 0.f};
#pragma unroll
    for (int r = 0; r < 4; ++r) {
      const int s = w * 16 + g * 4 + r;
#pragma unroll
      for (int n = 0; n < 4; ++n) {
        const int t2 = n * 16 + tcol;
        const float v = (t2 <= s) ? acc_s[n][r] : 0.f;
        dintra[r] += v;
        Sb[s * 64 + (t2 ^ ((s & 7) << 3))] = f2bf(v);
      }
    }
#pragma unroll
    for (int off = 1; off < 16; off <<= 1)
#pragma unroll
      for (int r = 0; r < 4; ++r) dintra[r] += __shfl_xor(dintra[r], off, 64);
    if (tcol == 0) {
#pragma unroll
      for (int r = 0; r < 4; ++r) denl[w * 16 + g * 4 + r] = dintra[r];
    }
  }
  // stage SpxT [d][m] (SchB is [m][d], bf16): 8-row gather + b128 swizzled write
  {
    const unsigned short* Sp = SchB + (((size_t)b * HH + h) * NC + c) * (MM * DH);
    for (int i = tid; i < 1024; i += 256) {
      const int d = i & 63, oct = i >> 6;   // m0 = oct*8
      const unsigned short* src = Sp + (size_t)(oct * 8) * DH + d;
      bf16x8 v;
#pragma unroll
      for (int j = 0; j < 8; ++j) v[j] = (short)src[(size_t)j * DH];
      *reinterpret_cast<bf16x8*>(&SpxT[d * 128 + ((oct * 8) ^ ((d & 15) << 3))]) = v;
    }
  }
  __syncthreads();

  // phase 2: O = tril(S)@V + Qc@Sprev
  f32x4 acc_o[4] = {};
#pragma unroll
  for (int kc = 0; kc < 2; ++kc) {
    const int k = kc * 32 + kk;
    const bf16x8 as = *reinterpret_cast<const bf16x8*>(&Sb[sA * 64 + (k ^ ((sA & 7) << 3))]);
#pragma unroll
    for (int n = 0; n < 4; ++n) {
      const int dB = n * 16 + (lane & 15);
      const bf16x8 bv = *reinterpret_cast<const bf16x8*>(&VT[dB * 64 + (k ^ ((dB & 7) << 3))]);
      acc_o[n] = __builtin_amdgcn_mfma_f32_16x16x32_bf16(as, bv, acc_o[n], 0, 0, 0);
    }
  }
#pragma unroll
  for (int kc = 0; kc < 4; ++kc) {
    const int k = kc * 32 + kk;
    const bf16x8 aq = *reinterpret_cast<const bf16x8*>(&Qc[sA * 128 + (k ^ ((sA & 15) << 3))]);
#pragma unroll
    for (int n = 0; n < 4; ++n) {
      const int dB = n * 16 + (lane & 15);
      const bf16x8 bs = *reinterpret_cast<const bf16x8*>(&SpxT[dB * 128 + (k ^ ((dB & 15) << 3))]);
      acc_o[n] = __builtin_amdgcn_mfma_f32_16x16x32_bf16(aq, bs, acc_o[n], 0, 0, 0);
    }
  }
  // den_inter = q . skp
  {
    const int s2 = tid >> 2, part = tid & 3;
    float p = 0.f;
#pragma unroll
    for (int j = 0; j < 32; ++j) {
      const int m = part * 32 + j;
      p += bf2f(Qc[s2 * 128 + (m ^ ((s2 & 15) << 3))]) * skp[m];
    }
    p += __shfl_xor(p, 1, 64);
    p += __shfl_xor(p, 2, 64);
    if (part == 0) denl[s2] += p + 1e-6f;
  }
  __syncthreads();

  {
    const int g = lane >> 4;
    const int dcol = lane & 15;
#pragma unroll
    for (int r = 0; r < 4; ++r) {
      const int s = w * 16 + g * 4 + r;
      const float dinv = 1.f / denl[s];
#pragma unroll
      for (int n = 0; n < 4; ++n)
        att[(srow0 + s) * DM + h * DH + n * 16 + dcol] = f2bf(acc_o[n][r] * dinv);
    }
  }
}

// ---------------------------------------------------------------------------
// out = LayerNorm(a + b0 + b1) * g + beta; bres slices are bf16.
// Optional bf16 shadow copy.
// ---------------------------------------------------------------------------
template<int WBF>
__global__ __launch_bounds__(256)
void add_ln(const float* __restrict__ a, const unsigned short* __restrict__ bres, size_t sstride,
            const float* __restrict__ g, const float* __restrict__ be,
            float* __restrict__ out, unsigned short* __restrict__ outbf)
{
  const int row = blockIdx.x;
  const int t = threadIdx.x;
  const size_t base = (size_t)row * DM;
  float x0 = a[base + t]       + bf2f(bres[base + t])       + bf2f(bres[sstride + base + t]);
  float x1 = a[base + t + 256] + bf2f(bres[base + t + 256]) + bf2f(bres[sstride + base + t + 256]);
  __shared__ float red[8];
  float ssum = x0 + x1;
#pragma unroll
  for (int off = 32; off > 0; off >>= 1) ssum += __shfl_xor(ssum, off, 64);
  const int wid = t >> 6, lid = t & 63;
  if (lid == 0) red[wid] = ssum;
  __syncthreads();
  const float mu = (red[0] + red[1] + red[2] + red[3]) * (1.f / DM);
  const float d0 = x0 - mu, d1 = x1 - mu;
  float sv = d0 * d0 + d1 * d1;
#pragma unroll
  for (int off = 32; off > 0; off >>= 1) sv += __shfl_xor(sv, off, 64);
  if (lid == 0) red[4 + wid] = sv;
  __syncthreads();
  const float var = (red[4] + red[5] + red[6] + red[7]) * (1.f / DM);
  const float rs = rsqrtf(var + 1e-5f);
  const float o0 = d0 * rs * g[t]       + be[t];
  const float o1 = d1 * rs * g[t + 256] + be[t + 256];
  out[base + t]       = o0;
  out[base + t + 256] = o1;
  if (WBF) {
    outbf[base + t]       = f2bf(o0);
    outbf[base + t + 256] = f2bf(o1);
  }
}

// ---------------------------------------------------------------------------
// Host-side launch
// ---------------------------------------------------------------------------
extern "C" void kernel_launch(void* const* d_in, const int* in_sizes, int n_in,
                              void* d_out, int out_size, void* d_ws, size_t ws_size,
                              hipStream_t stream)
{
  const float* x      = (const float*)d_in[0];
  const float* Wq     = (const float*)d_in[1];
  const float* bq     = (const float*)d_in[2];
  const float* Wk     = (const float*)d_in[3];
  const float* bk     = (const float*)d_in[4];
  const float* Wv     = (const float*)d_in[5];
  const float* bv     = (const float*)d_in[6];
  const float* Wo     = (const float*)d_in[7];
  const float* bo     = (const float*)d_in[8];
  const float* W1     = (const float*)d_in[9];
  const float* b1     = (const float*)d_in[10];
  const float* W2     = (const float*)d_in[11];
  const float* b2     = (const float*)d_in[12];
  const float* ln1g   = (const float*)d_in[13];
  const float* ln1b   = (const float*)d_in[14];
  const float* ln2g   = (const float*)d_in[15];
  const float* ln2b   = (const float*)d_in[16];
  const float* freqs  = (const float*)d_in[17];
  const float* offs   = (const float*)d_in[18];
  const float* gains  = (const float*)d_in[19];
  const float* noise  = (const float*)d_in[20];
  const float* gate   = (const float*)d_in[21];
  const float* gnoise = (const float*)d_in[22];
  const float* omega  = (const float*)d_in[23];

  float* ws = (float*)d_ws;
  size_t o = 0;
  float* curf = ws + o; o += (size_t)BB * SS * DM;              // 2M f
  unsigned short* qkvb = (unsigned short*)(ws + o); o += (size_t)BB * SS * QKV_N / 2;  // bf16, hbuf alias
  float* Sch  = ws + o; o += (size_t)BB * HH * NC * MM * DH;    // f32-sized region (attp/ybuf alias)
  float* kch  = ws + o; o += (size_t)BB * HH * NC * MM;
  float* bqkv = ws + o; o += (size_t)LL * QKV_N;
  float2* offcs = (float2*)(ws + o); o += (size_t)LL * HH * DH * NS * 2;
  float* omgf = ws + o; o += (size_t)LL * HH * DH * NS;
  unsigned short* zpb = (unsigned short*)(ws + o); o += (size_t)LL * HH * RR * 10 * DH / 2;  // bf16
  unsigned short* QfKfB = (unsigned short*)(ws + o); o += (size_t)2 * BB * SS * HH * MM / 2; // 16.8MB
  unsigned short* attb  = (unsigned short*)(ws + o); o += (size_t)BB * SS * DM / 2;
  unsigned short* h_bf  = (unsigned short*)(ws + o); o += (size_t)BB * SS * DM / 2;
  unsigned short* curbf = (unsigned short*)(ws + o); o += (size_t)BB * SS * DM / 2;
  unsigned short* Wqkvt = (unsigned short*)(ws + o); o += (size_t)LL * QKV_N * DM / 2;
  unsigned short* Wot   = (unsigned short*)(ws + o); o += (size_t)LL * DM * DM / 2;
  unsigned short* W1t   = (unsigned short*)(ws + o); o += (size_t)LL * DF * DM / 2;
  unsigned short* W2t   = (unsigned short*)(ws + o); o += (size_t)LL * DM * DF / 2;
  unsigned short* omgT  = (unsigned short*)(ws + o); o += (size_t)LL * 4096 / 2;
  unsigned short* wbb   = (unsigned short*)(ws + o); o += (size_t)LL * HH * RR * DH / 2;

  const size_t SLICE = (size_t)BB * SS * DM;      // 2M elements per C slice
  unsigned short* SchB  = (unsigned short*)Sch;   // bf16 Sch in first half of region
  unsigned short* attpB = (unsigned short*)Sch;   // 2 bf16 slices over dead-Sch region (8MB)
  unsigned short* ybufB = (unsigned short*)Sch;   // same region, sequential
  float* hbuf = (float*)qkvb;                     // 2M floats of 3.14M (qkv dead after attn_out)
  unsigned short* midbf = QfKfB;                  // FFN mid over QfKf (sequential)
  unsigned short* KfB   = QfKfB + (size_t)BB * SS * HH * MM;

  const int MROWS = BB * SS;  // 4096

  prep_all<<<PR_CV, 256, 0, stream>>>(x, Wq, Wk, Wv, Wo, W1, W2, omega,
                                      bq, bk, bv, gains, noise, gate, gnoise, offs, freqs,
                                      curbf, Wqkvt, Wot, W1t, W2t, omgT, bqkv,
                                      zpb, wbb, offcs, omgf);

  for (int l = 0; l < LL; ++l) {
    const float* in = (l == 0) ? x : curf;

    gemm_mfma_128<0, 1, 1><<<dim3(QKV_N / 128, MROWS / 128), 256, 0, stream>>>(
        curbf, Wqkvt + (size_t)l * QKV_N * DM, bqkv + (size_t)l * QKV_N,
        (float*)nullptr, qkvb, MROWS, QKV_N, DM);

    spe_xhat<<<dim3(SS, HH), 256, 0, stream>>>(
        omgf + (size_t)l * HH * DH * NS, offcs + (size_t)l * HH * DH * NS,
        zpb + (size_t)l * HH * RR * 10 * DH, wbb + (size_t)l * HH * RR * DH,
        qkvb, omgT + (size_t)l * 4096, QfKfB);

    attn_chunk_sums<<<dim3(NC, HH, BB), 256, 0, stream>>>(KfB, qkvb, SchB, kch);
    attn_scan<<<dim3(BB * HH, 8), 256, 0, stream>>>(SchB, kch);
    attn_out<<<dim3(NC, HH, BB), 256, 0, stream>>>(QfKfB, qkvb, SchB, kch, attb);

    // output projection, split-K=2, bf16 slices (over dead-Sch region)
    gemm_mfma_128<0, 1, 2><<<dim3(DM / 128, MROWS / 128, 2), 256, 0, stream>>>(
        attb, Wot + (size_t)l * DM * DM, bo + (size_t)l * DM,
        (float*)nullptr, attpB, MROWS, DM, DM);

    add_ln<1><<<MROWS, 256, 0, stream>>>(in, attpB, SLICE,
        ln1g + (size_t)l * DM, ln1b + (size_t)l * DM, hbuf, h_bf);

    gemm_mfma_128<1, 1, 1><<<dim3(DF / 128, MROWS / 128), 256, 0, stream>>>(
        h_bf, W1t + (size_t)l * DF * DM, b1 + (size_t)l * DF, (float*)nullptr, midbf, MROWS, DF, DM);

    // FFN down-projection, split-K=2, bf16 slices
    gemm_mfma_128<0, 1, 2><<<dim3(DM / 128, MROWS / 128, 2), 256, 0, stream>>>(
        midbf, W2t + (size_t)l * DM * DF, b2 + (size_t)l * DM,
        (float*)nullptr, ybufB, MROWS, DM, DF);

    if (l == LL - 1) {
      add_ln<0><<<MROWS, 256, 0, stream>>>(hbuf, ybufB, SLICE,
          ln2g + (size_t)l * DM, ln2b + (size_t)l * DM, (float*)d_out, (unsigned short*)nullptr);
    } else {
      add_ln<1><<<MROWS, 256, 0, stream>>>(hbuf, ybufB, SLICE,
          ln2g + (size_t)l * DM, ln2b + (size_t)l * DM, curf, curbf);
    }
  }
}

// Round 23
// 623.832 us; speedup vs baseline: 1.0660x; 1.0660x over previous
//
#include <hip/hip_runtime.h>
#include <math.h>

// ---------------------------------------------------------------------------
// Model constants
// ---------------------------------------------------------------------------
#define BB 4
#define SS 1024
#define LL 4
#define HH 8
#define DM 512
#define DF 2048
#define DH 64
#define NS 5
#define RR 32
#define MM 128          // favor feature dims
#define NC 16           // attention chunks
#define CHK 64          // chunk size
#define QKV_N 1536      // packed q|k|v width

#define INV_SQRT10   0.316227766016838f
#define INV_SCALE    0.148650889375340f   // 1/(R*DH)^0.25
#define TEMP_SCALE   0.353553390593274f   // 64^-0.25
#define INV_SQRT_M   0.088388347648318f   // 1/sqrt(128)
#define TWO_PI       6.283185307179586f
#define PI_F         3.141592653589793f

typedef __attribute__((ext_vector_type(8))) short bf16x8;
typedef __attribute__((ext_vector_type(4))) float f32x4;

__device__ __forceinline__ unsigned short f2bf(float f) {
  union { float f; unsigned int u; } v; v.f = f;
  unsigned int r = v.u + 0x7FFFu + ((v.u >> 16) & 1u);
  return (unsigned short)(r >> 16);
}

__device__ __forceinline__ float bf2f(unsigned short u) {
  union { unsigned int u; float f; } v; v.u = (unsigned int)u << 16;
  return v.f;
}

__device__ __forceinline__ void gld_lds16(const unsigned short* g, unsigned short* l) {
  __builtin_amdgcn_global_load_lds((const __attribute__((address_space(1))) void*)g,
                                   (__attribute__((address_space(3))) void*)l,
                                   16, 0, 0);
}

// ---------------------------------------------------------------------------
// bf16 MFMA GEMM, 128x64 tile. SPLITK>1: blockIdx.z owns K-slice, writes its
// own C slice (+ kz*M*N, f32 or bf16 per OUT_BF); bias added on slice 0 only.
// ---------------------------------------------------------------------------
template<int RELU, int OUT_BF, int SPLITK>
__global__ __launch_bounds__(256)
void gemm_mfma_n64(const unsigned short* __restrict__ A, const unsigned short* __restrict__ Bt,
                   const float* __restrict__ bias, float* __restrict__ Cf,
                   unsigned short* __restrict__ Cbf, int M, int N, int K)
{
  __shared__ unsigned short As[128 * 32];
  __shared__ unsigned short Bs[64 * 32];
  const int tid  = threadIdx.x;
  const int w    = tid >> 6;
  const int lane = tid & 63;
  const int row0 = blockIdx.y * 128;
  const int col0 = blockIdx.x * 64;
  const int kz   = (SPLITK > 1) ? blockIdx.z : 0;
  const int Ks   = K / SPLITK;
  const int kbeg = kz * Ks;
  const int wr = (w >> 1) * 64;
  const int wc = (w & 1) * 32;
  const int c0 = w * 2, c1 = w * 2 + 1;
  const int m0 = c0 * 16 + (lane >> 2);
  const int m1 = c1 * 16 + (lane >> 2);
  const int mb = w * 16 + (lane >> 2);
  const int kA = (lane & 3) * 8;

  f32x4 acc[4][2] = {};

  for (int k0 = kbeg; k0 < kbeg + Ks; k0 += 32) {
    gld_lds16(&A [(size_t)(row0 + m0) * K + k0 + kA], &As[c0 * 512]);
    gld_lds16(&A [(size_t)(row0 + m1) * K + k0 + kA], &As[c1 * 512]);
    gld_lds16(&Bt[(size_t)(col0 + mb) * K + k0 + kA], &Bs[w * 512]);
    __syncthreads();
    const int rA = wr + (lane & 15);
    const int rB = wc + (lane & 15);
    const int kk = (lane >> 4) * 8;
    bf16x8 af[4], bfr[2];
#pragma unroll
    for (int i = 0; i < 4; ++i)
      af[i]  = *reinterpret_cast<const bf16x8*>(&As[(rA + i * 16) * 32 + kk]);
#pragma unroll
    for (int i = 0; i < 2; ++i)
      bfr[i] = *reinterpret_cast<const bf16x8*>(&Bs[(rB + i * 16) * 32 + kk]);
#pragma unroll
    for (int mi = 0; mi < 4; ++mi)
#pragma unroll
      for (int ni = 0; ni < 2; ++ni)
        acc[mi][ni] = __builtin_amdgcn_mfma_f32_16x16x32_bf16(af[mi], bfr[ni], acc[mi][ni], 0, 0, 0);
    __syncthreads();
  }
  const int cr = (lane >> 4) * 4;
  const int cc = lane & 15;
  float* Cfo = Cf ? (Cf + (size_t)kz * M * N) : Cf;
  unsigned short* Cbo = Cbf ? (Cbf + (size_t)kz * M * N) : Cbf;
#pragma unroll
  for (int mi = 0; mi < 4; ++mi) {
#pragma unroll
    for (int ni = 0; ni < 2; ++ni) {
      const int col = col0 + wc + ni * 16 + cc;
      const float bv = (kz == 0) ? bias[col] : 0.f;
#pragma unroll
      for (int r = 0; r < 4; ++r) {
        const int row = row0 + wr + mi * 16 + cr + r;
        float v = acc[mi][ni][r] + bv;
        if (RELU) v = fmaxf(v, 0.f);
        if (OUT_BF) Cbo[(size_t)row * N + col] = f2bf(v);
        else        Cfo[(size_t)row * N + col] = v;
      }
    }
  }
}

// ---------------------------------------------------------------------------
// prep_all: fuses ALL prologue work into one launch.
// ---------------------------------------------------------------------------
#define PR_T0   4096
#define PR_W1   8192
#define PR_W2   12288
#define PR_OM   12304
#define PR_PB   12328
#define PR_SP   15224
#define PR_CV   17272

__global__ __launch_bounds__(256)
void prep_all(const float* __restrict__ x,
              const float* __restrict__ Wq, const float* __restrict__ Wk,
              const float* __restrict__ Wv, const float* __restrict__ Wo,
              const float* __restrict__ W1, const float* __restrict__ W2,
              const float* __restrict__ omega,
              const float* __restrict__ bq, const float* __restrict__ bk,
              const float* __restrict__ bv,
              const float* __restrict__ gains, const float* __restrict__ noise,
              const float* __restrict__ gate, const float* __restrict__ gnoise,
              const float* __restrict__ offsets, const float* __restrict__ freqs,
              unsigned short* __restrict__ curbf,
              unsigned short* __restrict__ Wqkvt, unsigned short* __restrict__ Wot,
              unsigned short* __restrict__ W1t, unsigned short* __restrict__ W2t,
              unsigned short* __restrict__ omgT,
              float* __restrict__ bqkv,
              unsigned short* __restrict__ zpb, unsigned short* __restrict__ wbb,
              float2* __restrict__ offcs, float* __restrict__ omg)
{
  const int bid = blockIdx.x;
  const int tid = threadIdx.x;

  if (bid < PR_OM) {
    // ---- transpose tasks ----
    const float* W; unsigned short* Wt; int K, N, bx, by;
    if (bid < PR_T0) {
      const int mat = bid >> 10;          // 0..3
      const int local = bid & 1023;
      bx = local & 15; by = (local >> 4) & 15;
      const int l = local >> 8;
      K = DM; N = DM;
      if (mat == 0)      { W = Wq + (size_t)l * DM * DM; Wt = Wqkvt + (size_t)l * QKV_N * DM; }
      else if (mat == 1) { W = Wk + (size_t)l * DM * DM; Wt = Wqkvt + (size_t)l * QKV_N * DM + (size_t)512 * DM; }
      else if (mat == 2) { W = Wv + (size_t)l * DM * DM; Wt = Wqkvt + (size_t)l * QKV_N * DM + (size_t)1024 * DM; }
      else               { W = Wo + (size_t)l * DM * DM; Wt = Wot + (size_t)l * DM * DM; }
    } else if (bid < PR_W1) {
      const int local = bid - PR_T0;
      bx = local & 63; by = (local >> 6) & 15;
      const int l = local >> 10;
      K = DM; N = DF;
      W = W1 + (size_t)l * DM * DF; Wt = W1t + (size_t)l * DF * DM;
    } else if (bid < PR_W2) {
      const int local = bid - PR_W1;
      bx = local & 15; by = (local >> 4) & 63;
      const int l = local >> 10;
      K = DF; N = DM;
      W = W2 + (size_t)l * DF * DM; Wt = W2t + (size_t)l * DM * DF;
    } else {
      const int local = bid - PR_W2;
      bx = local & 1; by = (local >> 1) & 1;
      const int l = local >> 2;
      K = DH; N = MM / 2;
      W = omega + (size_t)l * DH * (MM / 2); Wt = omgT + (size_t)l * 4096;
    }
    __shared__ float tile[32][33];
    const int k0 = by * 32, n0 = bx * 32;
    const int tx = tid & 31, ty = tid >> 5;
#pragma unroll
    for (int j = 0; j < 4; ++j)
      tile[ty + 8 * j][tx] = W[(size_t)(k0 + ty + 8 * j) * N + n0 + tx];
    __syncthreads();
#pragma unroll
    for (int j = 0; j < 4; ++j)
      Wt[(size_t)(n0 + ty + 8 * j) * K + k0 + tx] = f2bf(tile[tx][ty + 8 * j]);
  } else if (bid < PR_PB) {
    // ---- pack_bias ----
    const int local = bid - PR_OM;
    const int l = local / 6;
    const int i = (local % 6) * 256 + tid;
    if (i < QKV_N)
      bqkv[l * QKV_N + i] = (i < 512) ? bq[l * DM + i] : (i < 1024) ? bk[l * DM + i - 512]
                                                                    : bv[l * DM + i - 1024];
  } else if (bid < PR_SP) {
    // ---- spe precompute ----
    const int i = (bid - PR_PB) * 256 + tid;
    const int NZ = LL * HH * RR * 10 * DH;      // 655360
    const int NW = LL * HH * RR * DH;           // 65536
    const int NO = LL * HH * DH * NS;           // 10240
    if (i < NZ) {
      const int d = i & 63;
      int j = i >> 6;
      const int k = j % 10; j /= 10;
      const int r = j & 31; j >>= 5;
      const int h = j & 7;  const int l = j >> 3;
      const int lhd = (l * HH + h) * DH + d;
      const float ga = gains[lhd * NS + (k >> 1)];
      const float sp = (ga > 20.f) ? ga : log1pf(__expf(ga));
      const float gg = 1.f / (1.f + __expf(-gate[lhd]));
      const float c1 = sqrtf(fmaxf(1.f - gg, 0.f));
      const float nz = noise[((size_t)lhd * 10 + k) * 32 + r];
      zpb[i] = f2bf(nz * sp * c1 * (INV_SQRT10 * INV_SCALE * TEMP_SCALE));
    } else if (i < NZ + NW) {
      int j = i - NZ;
      const int d = j & 63; j >>= 6;
      const int r = j & 31; j >>= 5;
      const int h = j & 7;  const int l = j >> 3;
      const int lhd = (l * HH + h) * DH + d;
      const float gg = 1.f / (1.f + __expf(-gate[lhd]));
      wbb[i - NZ] = f2bf(sqrtf(gg) * gnoise[(size_t)lhd * 32 + r] * (INV_SCALE * TEMP_SCALE));
    } else if (i < NZ + NW + NO) {
      const int j = i - NZ - NW;
      float sn, cn;
      __sincosf(offsets[j], &sn, &cn);
      offcs[j] = make_float2(cn, sn);
    } else if (i < NZ + NW + 2 * NO) {
      const int j = i - NZ - NW - NO;
      omg[j] = PI_F / (1.f + __expf(-freqs[j]));
    }
  } else {
    // ---- x -> bf16 (vectorized by 4) ----
    const int i = (bid - PR_SP) * 256 + tid;
    const int n4 = BB * SS * DM / 4;
    if (i < n4) {
      const float4 v = reinterpret_cast<const float4*>(x)[i];
      ushort4 o;
      o.x = f2bf(v.x); o.y = f2bf(v.y); o.z = f2bf(v.z); o.w = f2bf(v.w);
      reinterpret_cast<ushort4*>(curbf)[i] = o;
    }
  }
}

// ---------------------------------------------------------------------------
// spe_xhat (fused, bf16 qkv, omg table): per (s,h). Builds qb/kb, MFMA ->
// xq/xk, then FAVOR: xq/xk back into rQ/rK rows 0-3, omega-MFMA, exp -> QfKfB.
// Tails (write-back + exp epilogue) spread across all 64 lanes via shfl.
// ---------------------------------------------------------------------------
__global__ __launch_bounds__(256)
void spe_xhat(const float* __restrict__ omg, const float2* __restrict__ offcs,
              const unsigned short* __restrict__ zpb, const unsigned short* __restrict__ wbb,
              const unsigned short* __restrict__ qkvb, const unsigned short* __restrict__ omgT,
              unsigned short* __restrict__ QfKfB)
{
  const int s = blockIdx.x;
  const int h = blockIdx.y;
  const int t = threadIdx.x;
  const int w = t >> 6;
  const int lane = t & 63;
  __shared__ float omqT[10][64];
  __shared__ float omkT[10][64];
  __shared__ unsigned short qbT[64 * 64];
  __shared__ unsigned short kbT[64 * 64];
  __shared__ unsigned short rQ[16 * 64];
  __shared__ unsigned short rK[16 * 64];
  __shared__ float hqp[4][8];
  __shared__ float hnl[8];   // [qk*4 + b]

  // phase A: sincos(omg*s) for k; q via rotation by precomputed offset sincos
  for (int e = t; e < DH * NS; e += 256) {
    const int d = e / NS, ns = e - d * NS;
    const float om = omg[(h * DH + d) * NS + ns];
    float sn, cn;
    __sincosf(om * (float)s, &sn, &cn);
    const float2 oc = offcs[(h * DH + d) * NS + ns];
    omkT[2 * ns][d]     = cn;
    omkT[2 * ns + 1][d] = sn;
    omqT[2 * ns][d]     = cn * oc.x - sn * oc.y;
    omqT[2 * ns + 1][d] = sn * oc.x + cn * oc.y;
  }
  // q/k row staging: vectorized bf16x8 copies (rows 0-3), zero rows 4-15
  if (t < 64) {
    const int isK = t >> 5;
    const int b = (t >> 3) & 3;
    const int j = t & 7;
    const unsigned short* src = qkvb + ((size_t)b * SS + s) * QKV_N + isK * 512 + h * DH + j * 8;
    unsigned short* dst = (isK ? rK : rQ) + b * 64 + ((j ^ b) << 3);
    *reinterpret_cast<bf16x8*>(dst) = *reinterpret_cast<const bf16x8*>(src);
  } else if (t < 256) {
    const int i = t - 64;   // 0..191
    bf16x8 z = {};
    if (i < 96) *reinterpret_cast<bf16x8*>(&rQ[256 + i * 8]) = z;
    else        *reinterpret_cast<bf16x8*>(&rK[256 + (i - 96) * 8]) = z;
  }
  __syncthreads();
  // phase B: build qbT/kbT. thread = (r = t>>3, d-octet dg = t&7)
  {
    const int r = t >> 3, dg = t & 7, d0 = dg * 8;
    float accq[8] = {}, acck[8] = {};
    const unsigned short* zr = zpb + (size_t)(h * RR + r) * 10 * 64 + d0;
#pragma unroll
    for (int k = 0; k < 10; ++k) {
      const bf16x8 zv = *reinterpret_cast<const bf16x8*>(zr + (size_t)k * 64);
      const float4 oq0 = *reinterpret_cast<const float4*>(&omqT[k][d0]);
      const float4 oq1 = *reinterpret_cast<const float4*>(&omqT[k][d0 + 4]);
      const float4 ok0 = *reinterpret_cast<const float4*>(&omkT[k][d0]);
      const float4 ok1 = *reinterpret_cast<const float4*>(&omkT[k][d0 + 4]);
      float zf[8];
#pragma unroll
      for (int j = 0; j < 8; ++j) zf[j] = bf2f((unsigned short)zv[j]);
      accq[0] += zf[0] * oq0.x; accq[1] += zf[1] * oq0.y;
      accq[2] += zf[2] * oq0.z; accq[3] += zf[3] * oq0.w;
      accq[4] += zf[4] * oq1.x; accq[5] += zf[5] * oq1.y;
      accq[6] += zf[6] * oq1.z; accq[7] += zf[7] * oq1.w;
      acck[0] += zf[0] * ok0.x; acck[1] += zf[1] * ok0.y;
      acck[2] += zf[2] * ok0.z; acck[3] += zf[3] * ok0.w;
      acck[4] += zf[4] * ok1.x; acck[5] += zf[5] * ok1.y;
      acck[6] += zf[6] * ok1.z; acck[7] += zf[7] * ok1.w;
    }
    bf16x8 qv, kv;
#pragma unroll
    for (int j = 0; j < 8; ++j) {
      qv[j] = (short)f2bf(accq[j]);
      kv[j] = (short)f2bf(acck[j]);
    }
    const int sd0 = d0 ^ ((r & 7) << 3);
    *reinterpret_cast<bf16x8*>(&qbT[r * 64 + sd0]) = qv;
    *reinterpret_cast<bf16x8*>(&kbT[r * 64 + sd0]) = kv;
    const bf16x8 wv = *reinterpret_cast<const bf16x8*>(&wbb[(size_t)(h * RR + r) * 64 + d0]);
    *reinterpret_cast<bf16x8*>(&qbT[(32 + r) * 64 + sd0]) = wv;
    *reinterpret_cast<bf16x8*>(&kbT[(32 + r) * 64 + sd0]) = wv;
  }
  __syncthreads();
  // MFMA: xq/xk = rows @ qb/kb
  f32x4 aq = {0.f, 0.f, 0.f, 0.f}, ak = {0.f, 0.f, 0.f, 0.f};
  const int arow = lane & 15;
  const int colr = w * 16 + (lane & 15);
#pragma unroll
  for (int kt = 0; kt < 2; ++kt) {
    const int g = kt * 4 + (lane >> 4);
    const bf16x8 fAq = *reinterpret_cast<const bf16x8*>(&rQ[arow * 64 + ((g ^ (arow & 7)) << 3)]);
    const bf16x8 fAk = *reinterpret_cast<const bf16x8*>(&rK[arow * 64 + ((g ^ (arow & 7)) << 3)]);
    const bf16x8 fBq = *reinterpret_cast<const bf16x8*>(&qbT[colr * 64 + ((g ^ (colr & 7)) << 3)]);
    const bf16x8 fBk = *reinterpret_cast<const bf16x8*>(&kbT[colr * 64 + ((g ^ (colr & 7)) << 3)]);
    aq = __builtin_amdgcn_mfma_f32_16x16x32_bf16(fAq, fBq, aq, 0, 0, 0);
    ak = __builtin_amdgcn_mfma_f32_16x16x32_bf16(fAk, fBk, ak, 0, 0, 0);
  }
  // half-norm partials (reduce over the 16 lanes of this lane-group)
  float rq[4], rk2[4];
#pragma unroll
  for (int r = 0; r < 4; ++r) { rq[r] = aq[r] * aq[r]; rk2[r] = ak[r] * ak[r]; }
#pragma unroll
  for (int off = 1; off < 16; off <<= 1) {
#pragma unroll
    for (int r = 0; r < 4; ++r) {
      rq[r]  += __shfl_xor(rq[r],  off, 64);
      rk2[r] += __shfl_xor(rk2[r], off, 64);
    }
  }
  if (lane == 0) {
#pragma unroll
    for (int r = 0; r < 4; ++r) { hqp[w][r] = rq[r]; hqp[w][4 + r] = rk2[r]; }
  }
  __syncthreads();   // all rQ/rK reads done; hqp complete

  // hn finalize into LDS
  if (t < 8) {
    const int b = t & 3;
    const int ko = (t >> 2) * 4;
    hnl[t] = 0.5f * (hqp[0][ko + b] + hqp[1][ko + b] + hqp[2][ko + b] + hqp[3][ko + b]);
  }
  // write xq/xk (bf16) back into rQ/rK rows 0-3 — spread across all 64 lanes.
  // Real MFMA rows live in lanes 0-15 (g=0): shfl with full exec, src 0-15.
  {
    const int rr = lane >> 4, cc2 = lane & 15;
    const float a0 = __shfl(aq[0], cc2, 64), a1 = __shfl(aq[1], cc2, 64);
    const float a2 = __shfl(aq[2], cc2, 64), a3 = __shfl(aq[3], cc2, 64);
    const float b0 = __shfl(ak[0], cc2, 64), b1 = __shfl(ak[1], cc2, 64);
    const float b2 = __shfl(ak[2], cc2, 64), b3 = __shfl(ak[3], cc2, 64);
    const float va = rr == 0 ? a0 : rr == 1 ? a1 : rr == 2 ? a2 : a3;
    const float vb = rr == 0 ? b0 : rr == 1 ? b1 : rr == 2 ? b2 : b3;
    const int d = w * 16 + cc2;
    rQ[rr * 64 + (d ^ (rr << 3))] = f2bf(va);
    rK[rr * 64 + (d ^ (rr << 3))] = f2bf(vb);
  }
  __syncthreads();

  // omega MFMA: u = xhat @ omgT^T (B-fragment straight from global/L2)
  f32x4 uq = {0.f, 0.f, 0.f, 0.f}, uk = {0.f, 0.f, 0.f, 0.f};
  const int ocol = w * 16 + (lane & 15);
#pragma unroll
  for (int kt = 0; kt < 2; ++kt) {
    const int g = kt * 4 + (lane >> 4);
    const bf16x8 fAq = *reinterpret_cast<const bf16x8*>(&rQ[arow * 64 + ((g ^ (arow & 7)) << 3)]);
    const bf16x8 fAk = *reinterpret_cast<const bf16x8*>(&rK[arow * 64 + ((g ^ (arow & 7)) << 3)]);
    const bf16x8 fB  = *reinterpret_cast<const bf16x8*>(&omgT[(size_t)ocol * 64 + g * 8]);
    uq = __builtin_amdgcn_mfma_f32_16x16x32_bf16(fAq, fB, uq, 0, 0, 0);
    uk = __builtin_amdgcn_mfma_f32_16x16x32_bf16(fAk, fB, uk, 0, 0, 0);
  }
  // epilogue: exp(+/-u - hn) -> QfKfB, spread across all 64 lanes
  {
    const int rr = lane >> 4, cc2 = lane & 15;
    const float q0 = __shfl(uq[0], cc2, 64), q1 = __shfl(uq[1], cc2, 64);
    const float q2 = __shfl(uq[2], cc2, 64), q3 = __shfl(uq[3], cc2, 64);
    const float k0 = __shfl(uk[0], cc2, 64), k1 = __shfl(uk[1], cc2, 64);
    const float k2 = __shfl(uk[2], cc2, 64), k3 = __shfl(uk[3], cc2, 64);
    const float vq = rr == 0 ? q0 : rr == 1 ? q1 : rr == 2 ? q2 : q3;
    const float vk = rr == 0 ? k0 : rr == 1 ? k1 : rr == 2 ? k2 : k3;
    const float hq = hnl[rr], hk = hnl[4 + rr];
    const size_t rowq = ((size_t)rr * SS + s) * HH + h;
    const size_t rowk = rowq + (size_t)BB * SS * HH;
    const int oc = w * 16 + cc2;
    QfKfB[rowq * MM + oc]      = f2bf(__expf( vq - hq) * INV_SQRT_M);
    QfKfB[rowq * MM + oc + 64] = f2bf(__expf(-vq - hq) * INV_SQRT_M);
    QfKfB[rowk * MM + oc]      = f2bf(__expf( vk - hk) * INV_SQRT_M);
    QfKfB[rowk * MM + oc + 64] = f2bf(__expf(-vk - hk) * INV_SQRT_M);
  }
}

// ---------------------------------------------------------------------------
// Attention pass A — MFMA: SchB[m][d] (bf16) = K^T V per chunk; kch f32.
// ---------------------------------------------------------------------------
__global__ __launch_bounds__(256)
void attn_chunk_sums(const unsigned short* __restrict__ KfB, const unsigned short* __restrict__ qkvb,
                     unsigned short* __restrict__ SchB, float* __restrict__ kch)
{
  const int c = blockIdx.x, h = blockIdx.y, b = blockIdx.z;
  const int tid = threadIdx.x;
  const int w = tid >> 6, lane = tid & 63;
  __shared__ unsigned short KcT[128 * 64];  // [m][t], t ^= (m&7)<<3
  __shared__ unsigned short VT[64 * 64];    // [d][t], t ^= (d&7)<<3
  const size_t srow0 = (size_t)b * SS + c * CHK;

  for (int i = tid; i < 8192; i += 256) {
    const int m = i & 127, t = i >> 7;
    KcT[m * 64 + (t ^ ((m & 7) << 3))] = KfB[((srow0 + t) * HH + h) * MM + m];
  }
  for (int i = tid; i < 512; i += 256) {
    const int d = i & 63, oct = i >> 6;
    const unsigned short* src = qkvb + (srow0 + oct * 8) * QKV_N + 1024 + h * DH + d;
    bf16x8 v;
#pragma unroll
    for (int j = 0; j < 8; ++j) v[j] = (short)src[(size_t)j * QKV_N];
    *reinterpret_cast<bf16x8*>(&VT[d * 64 + ((oct << 3) ^ ((d & 7) << 3))]) = v;
  }
  __syncthreads();

  const int kk = (lane >> 4) * 8;
  f32x4 acc[2][4] = {};
#pragma unroll
  for (int kc = 0; kc < 2; ++kc) {
    const int k = kc * 32 + kk;
#pragma unroll
    for (int mi = 0; mi < 2; ++mi) {
      const int mA = w * 32 + mi * 16 + (lane & 15);
      const bf16x8 a = *reinterpret_cast<const bf16x8*>(&KcT[mA * 64 + (k ^ ((mA & 7) << 3))]);
#pragma unroll
      for (int ni = 0; ni < 4; ++ni) {
        const int dB = ni * 16 + (lane & 15);
        const bf16x8 bb = *reinterpret_cast<const bf16x8*>(&VT[dB * 64 + (k ^ ((dB & 7) << 3))]);
        acc[mi][ni] = __builtin_amdgcn_mfma_f32_16x16x32_bf16(a, bb, acc[mi][ni], 0, 0, 0);
      }
    }
  }
  const size_t base = (((size_t)b * HH + h) * NC + c);
  unsigned short* So = SchB + base * (MM * DH);
  const int cr = (lane >> 4) * 4, cc = lane & 15;
#pragma unroll
  for (int mi = 0; mi < 2; ++mi)
#pragma unroll
    for (int ni = 0; ni < 4; ++ni)
#pragma unroll
      for (int r = 0; r < 4; ++r)
        So[(size_t)(w * 32 + mi * 16 + cr + r) * DH + ni * 16 + cc] = f2bf(acc[mi][ni][r]);
  // kch
  {
    const int m = tid >> 1, half = tid & 1;
    float ks = 0.f;
#pragma unroll
    for (int j = 0; j < 32; ++j) {
      const int t2 = half * 32 + j;
      ks += bf2f(KcT[m * 64 + (t2 ^ ((m & 7) << 3))]);
    }
    ks += __shfl_xor(ks, 1, 64);
    if (half == 0) kch[base * MM + m] = ks;
  }
}

// ---------------------------------------------------------------------------
// Attention pass B: exclusive scan over chunks (bf16 Sch, f32 accumulation,
// 4-wide vectorized accesses)
// ---------------------------------------------------------------------------
__global__ __launch_bounds__(256)
void attn_scan(unsigned short* __restrict__ SchB, float* __restrict__ kch)
{
  const int bh = blockIdx.x, part = blockIdx.y;
  const int t = threadIdx.x;
  unsigned short* base = SchB + (size_t)bh * NC * (MM * DH);
  {
    const int e0 = part * 1024 + t * 4;   // 4 contiguous elems per thread
    float run0 = 0.f, run1 = 0.f, run2 = 0.f, run3 = 0.f;
#pragma unroll
    for (int c = 0; c < NC; ++c) {
      ushort4* p = reinterpret_cast<ushort4*>(&base[(size_t)c * (MM * DH) + e0]);
      const ushort4 v = *p;
      ushort4 o;
      o.x = f2bf(run0); o.y = f2bf(run1); o.z = f2bf(run2); o.w = f2bf(run3);
      *p = o;
      run0 += bf2f(v.x); run1 += bf2f(v.y); run2 += bf2f(v.z); run3 += bf2f(v.w);
    }
  }
  if (part == 0 && t < MM) {
    float* kb2 = kch + (size_t)bh * NC * MM;
    float run = 0.f;
#pragma unroll
    for (int c = 0; c < NC; ++c) {
      const float v = kb2[c * MM + t];
      kb2[c * MM + t] = run;
      run += v;
    }
  }
}

// ---------------------------------------------------------------------------
// Attention pass C — MFMA (bf16 Qf/Kf, bf16 V, bf16 Sch)
// ---------------------------------------------------------------------------
__global__ __launch_bounds__(256)
void attn_out(const unsigned short* __restrict__ QfKfB, const unsigned short* __restrict__ qkvb,
              const unsigned short* __restrict__ SchB, const float* __restrict__ kch,
              unsigned short* __restrict__ att)
{
  const int c = blockIdx.x, h = blockIdx.y, b = blockIdx.z;
  const int tid = threadIdx.x;
  const int w = tid >> 6;
  const int lane = tid & 63;
  __shared__ unsigned short Qc[64 * 128];   // [s][m], m ^= (s&15)<<3
  __shared__ unsigned short Sb[64 * 64];    // [s][t], t ^= (s&7)<<3
  __shared__ unsigned short KVU[12288];     // ph1: Kc; ph2: SpxT@0, VT@8192
  __shared__ float skp[MM];
  __shared__ float denl[64];

  unsigned short* Kc   = KVU;
  unsigned short* SpxT = KVU;
  unsigned short* VT   = KVU + 8192;

  const size_t srow0 = (size_t)b * SS + c * CHK;
  const unsigned short* Qg = QfKfB + (srow0 * HH + h) * MM;
  const unsigned short* Kg = Qg + (size_t)BB * SS * HH * MM;

  if (tid < MM) skp[tid] = kch[(((size_t)b * HH + h) * NC + c) * MM + tid];

  // stage Qc, Kc (bf16x8 reads, swizzled b128 writes)
  for (int i = tid; i < 1024; i += 256) {
    const int s2 = i >> 4, m8 = (i & 15) * 8;
    const int sw = m8 ^ ((s2 & 15) << 3);
    *reinterpret_cast<bf16x8*>(&Qc[s2 * 128 + sw]) =
        *reinterpret_cast<const bf16x8*>(&Qg[(size_t)s2 * (HH * MM) + m8]);
    *reinterpret_cast<bf16x8*>(&Kc[s2 * 128 + sw]) =
        *reinterpret_cast<const bf16x8*>(&Kg[(size_t)s2 * (HH * MM) + m8]);
  }
  for (int i = tid; i < 512; i += 256) {
    const int d = i & 63, oct = i >> 6;
    const unsigned short* src = qkvb + (srow0 + oct * 8) * QKV_N + 1024 + h * DH + d;
    bf16x8 v;
#pragma unroll
    for (int j = 0; j < 8; ++j) v[j] = (short)src[(size_t)j * QKV_N];
    *reinterpret_cast<bf16x8*>(&VT[d * 64 + ((oct << 3) ^ ((d & 7) << 3))]) = v;
  }
  __syncthreads();

  // phase 1: S = Qc @ Kc^T
  const int sA = w * 16 + (lane & 15);
  const int kk = (lane >> 4) * 8;
  f32x4 acc_s[4] = {};
#pragma unroll
  for (int kc = 0; kc < 4; ++kc) {
    const int k = kc * 32 + kk;
    const bf16x8 aq = *reinterpret_cast<const bf16x8*>(&Qc[sA * 128 + (k ^ ((sA & 15) << 3))]);
#pragma unroll
    for (int n = 0; n < 4; ++n) {
      const int tB = n * 16 + (lane & 15);
      const bf16x8 bq = *reinterpret_cast<const bf16x8*>(&Kc[tB * 128 + (k ^ ((tB & 15) << 3))]);
      acc_s[n] = __builtin_amdgcn_mfma_f32_16x16x32_bf16(aq, bq, acc_s[n], 0, 0, 0);
    }
  }
  __syncthreads();   // Kc reads done; KVU reusable

  // mask + den_intra + write Sb
  {
    const int g = lane >> 4;
    const int tcol = lane & 15;
    float dintra[4] = {0.f, 0.f, 0.f, 0.f};
#pragma unroll
    for (int r = 0; r < 4; ++r) {
      const int s = w * 16 + g * 4 + r;
#pragma unroll
      for (int n = 0; n < 4; ++n) {
        const int t2 = n * 16 + tcol;
        const float v = (t2 <= s) ? acc_s[n][r] : 0.f;
        dintra[r] += v;
        Sb[s * 64 + (t2 ^ ((s & 7) << 3))] = f2bf(v);
      }
    }
#pragma unroll
    for (int off = 1; off < 16; off <<= 1)
#pragma unroll
      for (int r = 0; r < 4; ++r) dintra[r] += __shfl_xor(dintra[r], off, 64);
    if (tcol == 0) {
#pragma unroll
      for (int r = 0; r < 4; ++r) denl[w * 16 + g * 4 + r] = dintra[r];
    }
  }
  // stage SpxT [d][m] (SchB is [m][d], bf16): 8-row gather + b128 swizzled write
  {
    const unsigned short* Sp = SchB + (((size_t)b * HH + h) * NC + c) * (MM * DH);
    for (int i = tid; i < 1024; i += 256) {
      const int d = i & 63, oct = i >> 6;   // m0 = oct*8
      const unsigned short* src = Sp + (size_t)(oct * 8) * DH + d;
      bf16x8 v;
#pragma unroll
      for (int j = 0; j < 8; ++j) v[j] = (short)src[(size_t)j * DH];
      *reinterpret_cast<bf16x8*>(&SpxT[d * 128 + ((oct * 8) ^ ((d & 15) << 3))]) = v;
    }
  }
  __syncthreads();

  // phase 2: O = tril(S)@V + Qc@Sprev
  f32x4 acc_o[4] = {};
#pragma unroll
  for (int kc = 0; kc < 2; ++kc) {
    const int k = kc * 32 + kk;
    const bf16x8 as = *reinterpret_cast<const bf16x8*>(&Sb[sA * 64 + (k ^ ((sA & 7) << 3))]);
#pragma unroll
    for (int n = 0; n < 4; ++n) {
      const int dB = n * 16 + (lane & 15);
      const bf16x8 bv = *reinterpret_cast<const bf16x8*>(&VT[dB * 64 + (k ^ ((dB & 7) << 3))]);
      acc_o[n] = __builtin_amdgcn_mfma_f32_16x16x32_bf16(as, bv, acc_o[n], 0, 0, 0);
    }
  }
#pragma unroll
  for (int kc = 0; kc < 4; ++kc) {
    const int k = kc * 32 + kk;
    const bf16x8 aq = *reinterpret_cast<const bf16x8*>(&Qc[sA * 128 + (k ^ ((sA & 15) << 3))]);
#pragma unroll
    for (int n = 0; n < 4; ++n) {
      const int dB = n * 16 + (lane & 15);
      const bf16x8 bs = *reinterpret_cast<const bf16x8*>(&SpxT[dB * 128 + (k ^ ((dB & 15) << 3))]);
      acc_o[n] = __builtin_amdgcn_mfma_f32_16x16x32_bf16(aq, bs, acc_o[n], 0, 0, 0);
    }
  }
  // den_inter = q . skp
  {
    const int s2 = tid >> 2, part = tid & 3;
    float p = 0.f;
#pragma unroll
    for (int j = 0; j < 32; ++j) {
      const int m = part * 32 + j;
      p += bf2f(Qc[s2 * 128 + (m ^ ((s2 & 15) << 3))]) * skp[m];
    }
    p += __shfl_xor(p, 1, 64);
    p += __shfl_xor(p, 2, 64);
    if (part == 0) denl[s2] += p + 1e-6f;
  }
  __syncthreads();

  {
    const int g = lane >> 4;
    const int dcol = lane & 15;
#pragma unroll
    for (int r = 0; r < 4; ++r) {
      const int s = w * 16 + g * 4 + r;
      const float dinv = 1.f / denl[s];
#pragma unroll
      for (int n = 0; n < 4; ++n)
        att[(srow0 + s) * DM + h * DH + n * 16 + dcol] = f2bf(acc_o[n][r] * dinv);
    }
  }
}

// ---------------------------------------------------------------------------
// out = LayerNorm(a + b0 + b1) * g + beta; bres slices are bf16.
// Optional bf16 shadow copy.
// ---------------------------------------------------------------------------
template<int WBF>
__global__ __launch_bounds__(256)
void add_ln(const float* __restrict__ a, const unsigned short* __restrict__ bres, size_t sstride,
            const float* __restrict__ g, const float* __restrict__ be,
            float* __restrict__ out, unsigned short* __restrict__ outbf)
{
  const int row = blockIdx.x;
  const int t = threadIdx.x;
  const size_t base = (size_t)row * DM;
  float x0 = a[base + t]       + bf2f(bres[base + t])       + bf2f(bres[sstride + base + t]);
  float x1 = a[base + t + 256] + bf2f(bres[base + t + 256]) + bf2f(bres[sstride + base + t + 256]);
  __shared__ float red[8];
  float ssum = x0 + x1;
#pragma unroll
  for (int off = 32; off > 0; off >>= 1) ssum += __shfl_xor(ssum, off, 64);
  const int wid = t >> 6, lid = t & 63;
  if (lid == 0) red[wid] = ssum;
  __syncthreads();
  const float mu = (red[0] + red[1] + red[2] + red[3]) * (1.f / DM);
  const float d0 = x0 - mu, d1 = x1 - mu;
  float sv = d0 * d0 + d1 * d1;
#pragma unroll
  for (int off = 32; off > 0; off >>= 1) sv += __shfl_xor(sv, off, 64);
  if (lid == 0) red[4 + wid] = sv;
  __syncthreads();
  const float var = (red[4] + red[5] + red[6] + red[7]) * (1.f / DM);
  const float rs = rsqrtf(var + 1e-5f);
  const float o0 = d0 * rs * g[t]       + be[t];
  const float o1 = d1 * rs * g[t + 256] + be[t + 256];
  out[base + t]       = o0;
  out[base + t + 256] = o1;
  if (WBF) {
    outbf[base + t]       = f2bf(o0);
    outbf[base + t + 256] = f2bf(o1);
  }
}

// ---------------------------------------------------------------------------
// Host-side launch
// ---------------------------------------------------------------------------
extern "C" void kernel_launch(void* const* d_in, const int* in_sizes, int n_in,
                              void* d_out, int out_size, void* d_ws, size_t ws_size,
                              hipStream_t stream)
{
  const float* x      = (const float*)d_in[0];
  const float* Wq     = (const float*)d_in[1];
  const float* bq     = (const float*)d_in[2];
  const float* Wk     = (const float*)d_in[3];
  const float* bk     = (const float*)d_in[4];
  const float* Wv     = (const float*)d_in[5];
  const float* bv     = (const float*)d_in[6];
  const float* Wo     = (const float*)d_in[7];
  const float* bo     = (const float*)d_in[8];
  const float* W1     = (const float*)d_in[9];
  const float* b1     = (const float*)d_in[10];
  const float* W2     = (const float*)d_in[11];
  const float* b2     = (const float*)d_in[12];
  const float* ln1g   = (const float*)d_in[13];
  const float* ln1b   = (const float*)d_in[14];
  const float* ln2g   = (const float*)d_in[15];
  const float* ln2b   = (const float*)d_in[16];
  const float* freqs  = (const float*)d_in[17];
  const float* offs   = (const float*)d_in[18];
  const float* gains  = (const float*)d_in[19];
  const float* noise  = (const float*)d_in[20];
  const float* gate   = (const float*)d_in[21];
  const float* gnoise = (const float*)d_in[22];
  const float* omega  = (const float*)d_in[23];

  float* ws = (float*)d_ws;
  size_t o = 0;
  float* curf = ws + o; o += (size_t)BB * SS * DM;              // 2M f
  unsigned short* qkvb = (unsigned short*)(ws + o); o += (size_t)BB * SS * QKV_N / 2;  // bf16, hbuf alias
  float* Sch  = ws + o; o += (size_t)BB * HH * NC * MM * DH;    // f32-sized region (attp/ybuf alias)
  float* kch  = ws + o; o += (size_t)BB * HH * NC * MM;
  float* bqkv = ws + o; o += (size_t)LL * QKV_N;
  float2* offcs = (float2*)(ws + o); o += (size_t)LL * HH * DH * NS * 2;
  float* omgf = ws + o; o += (size_t)LL * HH * DH * NS;
  unsigned short* zpb = (unsigned short*)(ws + o); o += (size_t)LL * HH * RR * 10 * DH / 2;  // bf16
  unsigned short* QfKfB = (unsigned short*)(ws + o); o += (size_t)2 * BB * SS * HH * MM / 2; // 16.8MB
  unsigned short* attb  = (unsigned short*)(ws + o); o += (size_t)BB * SS * DM / 2;
  unsigned short* h_bf  = (unsigned short*)(ws + o); o += (size_t)BB * SS * DM / 2;
  unsigned short* curbf = (unsigned short*)(ws + o); o += (size_t)BB * SS * DM / 2;
  unsigned short* Wqkvt = (unsigned short*)(ws + o); o += (size_t)LL * QKV_N * DM / 2;
  unsigned short* Wot   = (unsigned short*)(ws + o); o += (size_t)LL * DM * DM / 2;
  unsigned short* W1t   = (unsigned short*)(ws + o); o += (size_t)LL * DF * DM / 2;
  unsigned short* W2t   = (unsigned short*)(ws + o); o += (size_t)LL * DM * DF / 2;
  unsigned short* omgT  = (unsigned short*)(ws + o); o += (size_t)LL * 4096 / 2;
  unsigned short* wbb   = (unsigned short*)(ws + o); o += (size_t)LL * HH * RR * DH / 2;

  const size_t SLICE = (size_t)BB * SS * DM;      // 2M elements per C slice
  unsigned short* SchB  = (unsigned short*)Sch;   // bf16 Sch in first half of region
  unsigned short* attpB = (unsigned short*)Sch;   // 2 bf16 slices over dead-Sch region (8MB)
  unsigned short* ybufB = (unsigned short*)Sch;   // same region, sequential
  float* hbuf = (float*)qkvb;                     // 2M floats of 3.14M (qkv dead after attn_out)
  unsigned short* midbf = QfKfB;                  // FFN mid over QfKf (sequential)
  unsigned short* KfB   = QfKfB + (size_t)BB * SS * HH * MM;

  const int MROWS = BB * SS;  // 4096

  prep_all<<<PR_CV, 256, 0, stream>>>(x, Wq, Wk, Wv, Wo, W1, W2, omega,
                                      bq, bk, bv, gains, noise, gate, gnoise, offs, freqs,
                                      curbf, Wqkvt, Wot, W1t, W2t, omgT, bqkv,
                                      zpb, wbb, offcs, omgf);

  for (int l = 0; l < LL; ++l) {
    const float* in = (l == 0) ? x : curf;

    gemm_mfma_n64<0, 1, 1><<<dim3(QKV_N / 64, MROWS / 128), 256, 0, stream>>>(
        curbf, Wqkvt + (size_t)l * QKV_N * DM, bqkv + (size_t)l * QKV_N,
        (float*)nullptr, qkvb, MROWS, QKV_N, DM);

    spe_xhat<<<dim3(SS, HH), 256, 0, stream>>>(
        omgf + (size_t)l * HH * DH * NS, offcs + (size_t)l * HH * DH * NS,
        zpb + (size_t)l * HH * RR * 10 * DH, wbb + (size_t)l * HH * RR * DH,
        qkvb, omgT + (size_t)l * 4096, QfKfB);

    attn_chunk_sums<<<dim3(NC, HH, BB), 256, 0, stream>>>(KfB, qkvb, SchB, kch);
    attn_scan<<<dim3(BB * HH, 8), 256, 0, stream>>>(SchB, kch);
    attn_out<<<dim3(NC, HH, BB), 256, 0, stream>>>(QfKfB, qkvb, SchB, kch, attb);

    // output projection, split-K=2, bf16 slices (over dead-Sch region)
    gemm_mfma_n64<0, 1, 2><<<dim3(DM / 64, MROWS / 128, 2), 256, 0, stream>>>(
        attb, Wot + (size_t)l * DM * DM, bo + (size_t)l * DM,
        (float*)nullptr, attpB, MROWS, DM, DM);

    add_ln<1><<<MROWS, 256, 0, stream>>>(in, attpB, SLICE,
        ln1g + (size_t)l * DM, ln1b + (size_t)l * DM, hbuf, h_bf);

    gemm_mfma_n64<1, 1, 1><<<dim3(DF / 64, MROWS / 128), 256, 0, stream>>>(
        h_bf, W1t + (size_t)l * DF * DM, b1 + (size_t)l * DF, (float*)nullptr, midbf, MROWS, DF, DM);

    // FFN down-projection, split-K=2, bf16 slices
    gemm_mfma_n64<0, 1, 2><<<dim3(DM / 64, MROWS / 128, 2), 256, 0, stream>>>(
        midbf, W2t + (size_t)l * DM * DF, b2 + (size_t)l * DM,
        (float*)nullptr, ybufB, MROWS, DM, DF);

    if (l == LL - 1) {
      add_ln<0><<<MROWS, 256, 0, stream>>>(hbuf, ybufB, SLICE,
          ln2g + (size_t)l * DM, ln2b + (size_t)l * DM, (float*)d_out, (unsigned short*)nullptr);
    } else {
      add_ln<1><<<MROWS, 256, 0, stream>>>(hbuf, ybufB, SLICE,
          ln2g + (size_t)l * DM, ln2b + (size_t)l * DM, curf, curbf);
    }
  }
}